// Round 1
// baseline (206711.621 us; speedup 1.0000x reference)
//
#include <hip/hip_runtime.h>
#include <math.h>

// ---------------------------------------------------------------------------
// SimpleRNN (2-layer LSTM, H=1024, T=4096 sequential steps, batch=1 effective)
//
// Phased design:
//   k_prep   : gather x (step-major), combine biases, zero sync flags
//   gemm_nt  : C[M,N] = A[M,K] @ B[N,K]^T + bias (both K-contiguous, "NT")
//              mode 0: row-major store; mode 1: scatter to (sample,step,out)
//   lstm_layer: persistent 512-block recurrence for one LSTM layer.
//              Block b owns hidden units {2b, 2b+1} => 8 gate rows of W_hh
//              kept in LDS (32 KB). Cross-block sync via 64 grouped flags
//              (8 blocks per flag, atomicAdd, agent scope). h history lives in
//              global, written/read with agent-scope atomics (sc0/sc1 -> MALL,
//              correct across non-coherent per-XCD L2s).
// ---------------------------------------------------------------------------

#define T_STEPS 4096
#define HID 1024

__global__ void k_prep(const float* __restrict__ inputs,
                       const float* __restrict__ b_ih0, const float* __restrict__ b_hh0,
                       const float* __restrict__ b_ih1, const float* __restrict__ b_hh1,
                       float* __restrict__ xg, float* __restrict__ bsum0,
                       float* __restrict__ b1sum, int* __restrict__ flags) {
  int i = blockIdx.x * 256 + threadIdx.x;   // grid covers 262144
  if (i < T_STEPS * 64) {
    int t = i >> 6, d = i & 63;
    // x[t] = inputs[sample = t%32, step = t/32, :]
    xg[i] = inputs[(t & 31) * 8192 + (t >> 5) * 64 + d];
  }
  if (i < 4096) {
    bsum0[i] = b_ih0[i] + b_hh0[i];
    b1sum[i] = b_ih1[i] + b_hh1[i];
  }
  if (i < 128) flags[i] = 0;                // flagsA[0:64], flagsC[64:128]
}

// C = A @ B^T + bias.  A: M x K, B: N x K (both row-major, K contiguous).
// 128x128 tile, BK=8, 256 threads, 8x8 micro-tile per thread.
__global__ __launch_bounds__(256) void gemm_nt(
    const float* __restrict__ A, const float* __restrict__ B,
    const float* __restrict__ bias, float* __restrict__ C,
    int M, int N, int K, int mode) {
  __shared__ float As[8][128];
  __shared__ float Bs[8][128];
  const int tid = threadIdx.x;
  const int bm = blockIdx.x * 128;
  const int bn = blockIdx.y * 128;
  const int tm = tid >> 4;        // 0..15
  const int tn = tid & 15;        // 0..15
  const int lr = tid >> 1;        // 0..127 (tile row for staging)
  const int lk = (tid & 1) * 4;   // 0 or 4

  float acc[8][8];
#pragma unroll
  for (int i = 0; i < 8; i++)
#pragma unroll
    for (int j = 0; j < 8; j++) acc[i][j] = 0.f;

  const float* Ap = A + (long)(bm + lr) * K + lk;
  const bool bvalid = (bn + lr) < N;
  const float* Bp = B + (long)(bvalid ? (bn + lr) : 0) * K + lk;

  for (int k0 = 0; k0 < K; k0 += 8) {
    float4 av = *(const float4*)(Ap + k0);
    float4 bv = bvalid ? *(const float4*)(Bp + k0) : make_float4(0.f, 0.f, 0.f, 0.f);
    As[lk + 0][lr] = av.x; As[lk + 1][lr] = av.y;
    As[lk + 2][lr] = av.z; As[lk + 3][lr] = av.w;
    Bs[lk + 0][lr] = bv.x; Bs[lk + 1][lr] = bv.y;
    Bs[lk + 2][lr] = bv.z; Bs[lk + 3][lr] = bv.w;
    __syncthreads();
#pragma unroll
    for (int kk = 0; kk < 8; kk++) {
      float a[8], b[8];
      *(float4*)&a[0] = *(const float4*)&As[kk][tm * 8];
      *(float4*)&a[4] = *(const float4*)&As[kk][tm * 8 + 4];
      *(float4*)&b[0] = *(const float4*)&Bs[kk][tn * 8];
      *(float4*)&b[4] = *(const float4*)&Bs[kk][tn * 8 + 4];
#pragma unroll
      for (int i = 0; i < 8; i++)
#pragma unroll
        for (int j = 0; j < 8; j++) acc[i][j] = fmaf(a[i], b[j], acc[i][j]);
    }
    __syncthreads();
  }

  const int n0 = bn + tn * 8;
  if (n0 < N) {   // N is always a multiple of 8; full 8-col vector valid
    float bb[8];
#pragma unroll
    for (int j = 0; j < 8; j++) bb[j] = bias[n0 + j];
#pragma unroll
    for (int i = 0; i < 8; i++) {
      int m = bm + tm * 8 + i;
      float4 v0, v1;
      v0.x = acc[i][0] + bb[0]; v0.y = acc[i][1] + bb[1];
      v0.z = acc[i][2] + bb[2]; v0.w = acc[i][3] + bb[3];
      v1.x = acc[i][4] + bb[4]; v1.y = acc[i][5] + bb[5];
      v1.z = acc[i][6] + bb[6]; v1.w = acc[i][7] + bb[7];
      if (mode == 0) {
        long o = (long)m * N + n0;
        *(float4*)&C[o] = v0; *(float4*)&C[o + 4] = v1;
      } else {
        // out[sample, step, o] with t=m: sample=m%32, step=m/32
        long o = (long)(m & 31) * 8192 + (long)(m >> 5) * 64 + n0;
        *(float4*)&C[o] = v0; *(float4*)&C[o + 4] = v1;
      }
    }
  }
}

__device__ __forceinline__ float sigmf(float x) { return 1.f / (1.f + expf(-x)); }

// Persistent recurrence for one LSTM layer.
// 512 blocks x 256 threads, 2 blocks/CU, all co-resident (37 KB LDS, 4 waves).
// Block b owns hidden units j0=2b, 2b+1; rows g*1024 + j (g = i,f,g,o).
// flags: 64 ints, flag[g] == 8*s  <=>  all 8 blocks of group g finished step s.
__global__ __launch_bounds__(256, 2) void lstm_layer(
    const float* __restrict__ pre,    // T x 4096, includes all biases
    const float* __restrict__ Whh,    // 4096 x 1024
    float* __restrict__ h_hist,       // T x 1024
    int* __restrict__ flags) {
  __shared__ float w_lds[8][1024];
  __shared__ float h_lds[1024];
  __shared__ float scr[8];      // scr[g*2+u] = dot for gate g, unit u
  __shared__ float pre_lds[8];
  const int b = blockIdx.x;
  const int tid = threadIdx.x;
  const int wave = tid >> 6;    // wave w handles gate w
  const int lane = tid & 63;
  const int j0 = b << 1;

#pragma unroll
  for (int rr = 0; rr < 8; rr++) {  // rr = g*2+u
    int row = (rr >> 1) * 1024 + j0 + (rr & 1);
    *(float4*)&w_lds[rr][tid * 4] = *(const float4*)&Whh[(long)row * 1024 + tid * 4];
  }
  float c_state = 0.f;   // valid in tid 0,1
  __syncthreads();

  for (int t = 0; t < T_STEPS; t++) {
    // prefetch this step's precomputed input contributions (overlaps the poll)
    float preval = 0.f;
    if (tid < 8)
      preval = pre[(long)t * 4096 + ((tid >> 1) << 10) + j0 + (tid & 1)];

    if (t > 0) {
      const int target = t << 3;
      bool ok;
      do {
        ok = true;
        if (tid < 64)
          ok = (__hip_atomic_load(&flags[tid], __ATOMIC_RELAXED,
                                  __HIP_MEMORY_SCOPE_AGENT) >= target);
      } while (!__syncthreads_and((int)ok));
      // fresh h[t-1]: agent-scope loads bypass non-coherent caches
      float* hp = h_hist + (long)(t - 1) * 1024 + tid * 4;
      float h0v = __hip_atomic_load(hp + 0, __ATOMIC_RELAXED, __HIP_MEMORY_SCOPE_AGENT);
      float h1v = __hip_atomic_load(hp + 1, __ATOMIC_RELAXED, __HIP_MEMORY_SCOPE_AGENT);
      float h2v = __hip_atomic_load(hp + 2, __ATOMIC_RELAXED, __HIP_MEMORY_SCOPE_AGENT);
      float h3v = __hip_atomic_load(hp + 3, __ATOMIC_RELAXED, __HIP_MEMORY_SCOPE_AGENT);
      h_lds[tid * 4 + 0] = h0v; h_lds[tid * 4 + 1] = h1v;
      h_lds[tid * 4 + 2] = h2v; h_lds[tid * 4 + 3] = h3v;
    } else {
      *(float4*)&h_lds[tid * 4] = make_float4(0.f, 0.f, 0.f, 0.f);
    }
    if (tid < 8) pre_lds[tid] = preval;
    __syncthreads();

    // dot: lane covers k in [lane*16, lane*16+16) for both of its gate's rows
    float hf[16];
    *(float4*)&hf[0]  = *(const float4*)&h_lds[lane * 16];
    *(float4*)&hf[4]  = *(const float4*)&h_lds[lane * 16 + 4];
    *(float4*)&hf[8]  = *(const float4*)&h_lds[lane * 16 + 8];
    *(float4*)&hf[12] = *(const float4*)&h_lds[lane * 16 + 12];
    const float* w0 = &w_lds[wave * 2 + 0][lane * 16];
    const float* w1 = &w_lds[wave * 2 + 1][lane * 16];
    float s0 = 0.f, s1 = 0.f;
#pragma unroll
    for (int m2 = 0; m2 < 16; m2++) {
      s0 = fmaf(w0[m2], hf[m2], s0);
      s1 = fmaf(w1[m2], hf[m2], s1);
    }
#pragma unroll
    for (int off = 32; off >= 1; off >>= 1) {
      s0 += __shfl_xor(s0, off, 64);
      s1 += __shfl_xor(s1, off, 64);
    }
    if (lane == 0) { scr[wave * 2 + 0] = s0; scr[wave * 2 + 1] = s1; }
    __syncthreads();

    if (tid < 2) {   // unit u = tid
      float gi = scr[0 + tid] + pre_lds[0 + tid];
      float gf = scr[2 + tid] + pre_lds[2 + tid];
      float gg = scr[4 + tid] + pre_lds[4 + tid];
      float go = scr[6 + tid] + pre_lds[6 + tid];
      c_state = sigmf(gf) * c_state + sigmf(gi) * tanhf(gg);
      float h = sigmf(go) * tanhf(c_state);
      __hip_atomic_store(&h_hist[(long)t * 1024 + j0 + tid], h,
                         __ATOMIC_RELAXED, __HIP_MEMORY_SCOPE_AGENT);
    }
    __syncthreads();   // barrier drains the write-through h stores (vmcnt)
    if (tid == 0)
      __hip_atomic_fetch_add(&flags[b >> 3], 1, __ATOMIC_RELEASE,
                             __HIP_MEMORY_SCOPE_AGENT);
  }
}

extern "C" void kernel_launch(void* const* d_in, const int* in_sizes, int n_in,
                              void* d_out, int out_size, void* d_ws, size_t ws_size,
                              hipStream_t stream) {
  const float* inputs = (const float*)d_in[0];
  const float* W_in  = (const float*)d_in[1];
  const float* b_in  = (const float*)d_in[2];
  const float* W_ih0 = (const float*)d_in[3];
  const float* W_hh0 = (const float*)d_in[4];
  const float* b_ih0 = (const float*)d_in[5];
  const float* b_hh0 = (const float*)d_in[6];
  const float* W_ih1 = (const float*)d_in[7];
  const float* W_hh1 = (const float*)d_in[8];
  const float* b_ih1 = (const float*)d_in[9];
  const float* b_hh1 = (const float*)d_in[10];
  const float* W_out = (const float*)d_in[11];
  const float* b_out = (const float*)d_in[12];
  float* out = (float*)d_out;

  char* ws = (char*)d_ws;
  float* pre_big = (float*)(ws);                          // 64 MB: pre0, then P1
  float* h0_all  = (float*)(ws + ((size_t)64 << 20));     // 16 MB
  float* zbuf    = (float*)(ws + ((size_t)80 << 20));     // 16 MB: z, then h1
  float* xg      = (float*)(ws + ((size_t)96 << 20));     // 1 MB
  float* bsum0   = (float*)(ws + ((size_t)97 << 20));     // 16 KB
  float* b1sum   = (float*)(ws + ((size_t)97 << 20) + 16384);
  int*   flags   = (int*)  (ws + ((size_t)97 << 20) + 32768);  // 128 ints
  int* flagsA = flags;
  int* flagsC = flags + 64;

  // 0) gather x, combine biases, zero flags
  k_prep<<<1024, 256, 0, stream>>>(inputs, b_ih0, b_hh0, b_ih1, b_hh1,
                                   xg, bsum0, b1sum, flags);
  // 1) z = x @ W_in^T + b_in            (4096 x 1024, K=64)
  gemm_nt<<<dim3(32, 8), 256, 0, stream>>>(xg, W_in, b_in, zbuf,
                                           T_STEPS, HID, 64, 0);
  // 2) pre0 = z @ W_ih0^T + (b_ih0+b_hh0)   (4096 x 4096, K=1024)
  gemm_nt<<<dim3(32, 32), 256, 0, stream>>>(zbuf, W_ih0, bsum0, pre_big,
                                            T_STEPS, 4096, HID, 0);
  // 3) layer-0 recurrence -> h0_all
  lstm_layer<<<512, 256, 0, stream>>>(pre_big, W_hh0, h0_all, flagsA);
  // 4) P1 = h0 @ W_ih1^T + (b_ih1+b_hh1)    (4096 x 4096, K=1024)
  gemm_nt<<<dim3(32, 32), 256, 0, stream>>>(h0_all, W_ih1, b1sum, pre_big,
                                            T_STEPS, 4096, HID, 0);
  // 5) layer-1 recurrence -> h1 (reuses zbuf)
  lstm_layer<<<512, 256, 0, stream>>>(pre_big, W_hh1, zbuf, flagsC);
  // 6) y = h1 @ W_out^T + b_out, scattered to (samples, steps, out)
  gemm_nt<<<dim3(32, 1), 256, 0, stream>>>(zbuf, W_out, b_out, out,
                                           T_STEPS, 64, HID, 1);
}

// Round 2
// 34190.430 us; speedup vs baseline: 6.0459x; 6.0459x over previous
//
#include <hip/hip_runtime.h>
#include <math.h>

// ---------------------------------------------------------------------------
// SimpleRNN (2-layer LSTM, H=1024, T=4096 sequential steps, batch=1 effective)
//
//   k_prep    : gather x (step-major), combine biases, zero sync flags
//   gemm_nt   : C[M,N] = A[M,K] @ B[N,K]^T + bias
//   lstm_layer: persistent 128-block recurrence. Block b owns 8 hidden units
//               (32 gate rows of W_hh in LDS, 128 KB, loaded once).
//               Sync: per-block release-store flag on its own 64B line
//               (no RMW); wave 0 polls all 128 flags with s_sleep backoff.
//               h history via agent-scope (MALL) loads/stores.
// ---------------------------------------------------------------------------

#define T_STEPS 4096
#define HID 1024
#define UPB 8            // hidden units per block
#define NBLK 128         // blocks per recurrence
#define FPAD 16          // ints per flag slot (64 B)

__global__ void k_prep(const float* __restrict__ inputs,
                       const float* __restrict__ b_ih0, const float* __restrict__ b_hh0,
                       const float* __restrict__ b_ih1, const float* __restrict__ b_hh1,
                       float* __restrict__ xg, float* __restrict__ bsum0,
                       float* __restrict__ b1sum, int* __restrict__ flags) {
  int i = blockIdx.x * 256 + threadIdx.x;   // grid covers 262144
  if (i < T_STEPS * 64) {
    int t = i >> 6, d = i & 63;
    // x[t] = inputs[sample = t%32, step = t/32, :]
    xg[i] = inputs[(t & 31) * 8192 + (t >> 5) * 64 + d];
  }
  if (i < 4096) {
    bsum0[i] = b_ih0[i] + b_hh0[i];
    b1sum[i] = b_ih1[i] + b_hh1[i];
  }
  if (i < 2 * NBLK * FPAD) flags[i] = 0;    // flagsA then flagsC
}

// C = A @ B^T + bias.  A: M x K, B: N x K (both row-major, K contiguous).
// 128x128 tile, BK=8, 256 threads, 8x8 micro-tile per thread.
__global__ __launch_bounds__(256) void gemm_nt(
    const float* __restrict__ A, const float* __restrict__ B,
    const float* __restrict__ bias, float* __restrict__ C,
    int M, int N, int K, int mode) {
  __shared__ float As[8][128];
  __shared__ float Bs[8][128];
  const int tid = threadIdx.x;
  const int bm = blockIdx.x * 128;
  const int bn = blockIdx.y * 128;
  const int tm = tid >> 4;
  const int tn = tid & 15;
  const int lr = tid >> 1;
  const int lk = (tid & 1) * 4;

  float acc[8][8];
#pragma unroll
  for (int i = 0; i < 8; i++)
#pragma unroll
    for (int j = 0; j < 8; j++) acc[i][j] = 0.f;

  const float* Ap = A + (long)(bm + lr) * K + lk;
  const bool bvalid = (bn + lr) < N;
  const float* Bp = B + (long)(bvalid ? (bn + lr) : 0) * K + lk;

  for (int k0 = 0; k0 < K; k0 += 8) {
    float4 av = *(const float4*)(Ap + k0);
    float4 bv = bvalid ? *(const float4*)(Bp + k0) : make_float4(0.f, 0.f, 0.f, 0.f);
    As[lk + 0][lr] = av.x; As[lk + 1][lr] = av.y;
    As[lk + 2][lr] = av.z; As[lk + 3][lr] = av.w;
    Bs[lk + 0][lr] = bv.x; Bs[lk + 1][lr] = bv.y;
    Bs[lk + 2][lr] = bv.z; Bs[lk + 3][lr] = bv.w;
    __syncthreads();
#pragma unroll
    for (int kk = 0; kk < 8; kk++) {
      float a[8], b[8];
      *(float4*)&a[0] = *(const float4*)&As[kk][tm * 8];
      *(float4*)&a[4] = *(const float4*)&As[kk][tm * 8 + 4];
      *(float4*)&b[0] = *(const float4*)&Bs[kk][tn * 8];
      *(float4*)&b[4] = *(const float4*)&Bs[kk][tn * 8 + 4];
#pragma unroll
      for (int i = 0; i < 8; i++)
#pragma unroll
        for (int j = 0; j < 8; j++) acc[i][j] = fmaf(a[i], b[j], acc[i][j]);
    }
    __syncthreads();
  }

  const int n0 = bn + tn * 8;
  if (n0 < N) {
    float bb[8];
#pragma unroll
    for (int j = 0; j < 8; j++) bb[j] = bias[n0 + j];
#pragma unroll
    for (int i = 0; i < 8; i++) {
      int m = bm + tm * 8 + i;
      float4 v0, v1;
      v0.x = acc[i][0] + bb[0]; v0.y = acc[i][1] + bb[1];
      v0.z = acc[i][2] + bb[2]; v0.w = acc[i][3] + bb[3];
      v1.x = acc[i][4] + bb[4]; v1.y = acc[i][5] + bb[5];
      v1.z = acc[i][6] + bb[6]; v1.w = acc[i][7] + bb[7];
      if (mode == 0) {
        long o = (long)m * N + n0;
        *(float4*)&C[o] = v0; *(float4*)&C[o + 4] = v1;
      } else {
        long o = (long)(m & 31) * 8192 + (long)(m >> 5) * 64 + n0;
        *(float4*)&C[o] = v0; *(float4*)&C[o + 4] = v1;
      }
    }
  }
}

__device__ __forceinline__ float sigmf(float x) { return 1.f / (1.f + expf(-x)); }

// Persistent recurrence for one LSTM layer.
// 128 blocks x 1024 threads, 1 block/CU (132.4 KB LDS), guaranteed co-resident.
// Block b owns units j0=8b..8b+7; local row rr = g*8+u <-> global g*1024+j0+u.
__global__ __launch_bounds__(1024, 1) void lstm_layer(
    const float* __restrict__ pre,    // T x 4096, includes all biases
    const float* __restrict__ Whh,    // 4096 x 1024
    float* __restrict__ h_hist,       // T x 1024
    int* __restrict__ flags) {        // NBLK slots, FPAD ints apart
  __shared__ float w_lds[32][HID];    // 128 KB
  __shared__ float h_lds[HID];        // 4 KB
  __shared__ float scr[32];
  __shared__ float pre_lds[32];
  const int b = blockIdx.x;
  const int tid = threadIdx.x;
  const int wave = tid >> 6;          // wave w owns rows 2w, 2w+1
  const int lane = tid & 63;
  const int j0 = b * UPB;

  {
    // stage 32 W_hh rows: thread covers row rr=tid>>5, 32 floats at (tid&31)*32
    int rr = tid >> 5;
    int part = tid & 31;
    const float* src = Whh + (long)((rr >> 3) * HID + j0 + (rr & 7)) * HID + part * 32;
    float* dst = &w_lds[rr][part * 32];
#pragma unroll
    for (int q = 0; q < 8; q++)
      *(float4*)(dst + q * 4) = *(const float4*)(src + q * 4);
  }
  float c_state = 0.f;                // valid in tid 0..7
  __syncthreads();

  for (int t = 0; t < T_STEPS; t++) {
    // prefetch this step's precomputed input contribution (overlaps the poll)
    float preval = 0.f;
    if (tid < 32)
      preval = pre[(long)t * 4096 + ((tid >> 3) << 10) + j0 + (tid & 7)];

    if (t > 0) {
      if (wave == 0) {                // only wave 0 polls; others sleep at barrier
        const int* f0 = flags + lane * FPAD;
        const int* f1 = flags + (lane + 64) * FPAD;
        for (;;) {
          int a = __hip_atomic_load(f0, __ATOMIC_RELAXED, __HIP_MEMORY_SCOPE_AGENT);
          int c = __hip_atomic_load(f1, __ATOMIC_RELAXED, __HIP_MEMORY_SCOPE_AGENT);
          if (__all(a >= t && c >= t)) break;
          __builtin_amdgcn_s_sleep(1);
        }
      }
      __syncthreads();
      // fresh h[t-1]: agent-scope loads are served at the coherence point
      h_lds[tid] = __hip_atomic_load(h_hist + (long)(t - 1) * HID + tid,
                                     __ATOMIC_RELAXED, __HIP_MEMORY_SCOPE_AGENT);
    } else {
      h_lds[tid] = 0.f;
    }
    if (tid < 32) pre_lds[tid] = preval;
    __syncthreads();

    // dot: lane covers k = lane + 64*m  (stride-64 -> bank-conflict-free)
    const float* w0 = &w_lds[wave * 2 + 0][0];
    const float* w1 = &w_lds[wave * 2 + 1][0];
    float s0 = 0.f, s1 = 0.f;
#pragma unroll
    for (int m = 0; m < 16; m++) {
      float hv = h_lds[lane + (m << 6)];
      s0 = fmaf(w0[lane + (m << 6)], hv, s0);
      s1 = fmaf(w1[lane + (m << 6)], hv, s1);
    }
#pragma unroll
    for (int off = 32; off >= 1; off >>= 1) {
      s0 += __shfl_xor(s0, off, 64);
      s1 += __shfl_xor(s1, off, 64);
    }
    if (lane == 0) { scr[wave * 2] = s0; scr[wave * 2 + 1] = s1; }
    __syncthreads();

    if (tid < UPB) {                  // unit u = tid
      float gi = scr[tid]      + pre_lds[tid];
      float gf = scr[8 + tid]  + pre_lds[8 + tid];
      float gg = scr[16 + tid] + pre_lds[16 + tid];
      float go = scr[24 + tid] + pre_lds[24 + tid];
      c_state = sigmf(gf) * c_state + sigmf(gi) * tanhf(gg);
      float h = sigmf(go) * tanhf(c_state);
      __hip_atomic_store(&h_hist[(long)t * HID + j0 + tid], h,
                         __ATOMIC_RELAXED, __HIP_MEMORY_SCOPE_AGENT);
    }
    __syncthreads();                  // barrier drain: h stores complete (vmcnt)
    if (tid == 0)                     // own-line release store, no RMW
      __hip_atomic_store(&flags[b * FPAD], t + 1, __ATOMIC_RELEASE,
                         __HIP_MEMORY_SCOPE_AGENT);
  }
}

extern "C" void kernel_launch(void* const* d_in, const int* in_sizes, int n_in,
                              void* d_out, int out_size, void* d_ws, size_t ws_size,
                              hipStream_t stream) {
  const float* inputs = (const float*)d_in[0];
  const float* W_in  = (const float*)d_in[1];
  const float* b_in  = (const float*)d_in[2];
  const float* W_ih0 = (const float*)d_in[3];
  const float* W_hh0 = (const float*)d_in[4];
  const float* b_ih0 = (const float*)d_in[5];
  const float* b_hh0 = (const float*)d_in[6];
  const float* W_ih1 = (const float*)d_in[7];
  const float* W_hh1 = (const float*)d_in[8];
  const float* b_ih1 = (const float*)d_in[9];
  const float* b_hh1 = (const float*)d_in[10];
  const float* W_out = (const float*)d_in[11];
  const float* b_out = (const float*)d_in[12];
  float* out = (float*)d_out;

  char* ws = (char*)d_ws;
  float* pre_big = (float*)(ws);                          // 64 MB: pre0, then P1
  float* h0_all  = (float*)(ws + ((size_t)64 << 20));     // 16 MB
  float* zbuf    = (float*)(ws + ((size_t)80 << 20));     // 16 MB: z, then h1
  float* xg      = (float*)(ws + ((size_t)96 << 20));     // 1 MB
  float* bsum0   = (float*)(ws + ((size_t)97 << 20));     // 16 KB
  float* b1sum   = (float*)(ws + ((size_t)97 << 20) + 16384);
  int*   flags   = (int*)  (ws + ((size_t)97 << 20) + 32768);
  int* flagsA = flags;                 // NBLK*FPAD ints
  int* flagsC = flags + NBLK * FPAD;

  // 0) gather x, combine biases, zero flags
  k_prep<<<1024, 256, 0, stream>>>(inputs, b_ih0, b_hh0, b_ih1, b_hh1,
                                   xg, bsum0, b1sum, flags);
  // 1) z = x @ W_in^T + b_in            (4096 x 1024, K=64)
  gemm_nt<<<dim3(32, 8), 256, 0, stream>>>(xg, W_in, b_in, zbuf,
                                           T_STEPS, HID, 64, 0);
  // 2) pre0 = z @ W_ih0^T + (b_ih0+b_hh0)   (4096 x 4096, K=1024)
  gemm_nt<<<dim3(32, 32), 256, 0, stream>>>(zbuf, W_ih0, bsum0, pre_big,
                                            T_STEPS, 4096, HID, 0);
  // 3) layer-0 recurrence -> h0_all
  lstm_layer<<<NBLK, 1024, 0, stream>>>(pre_big, W_hh0, h0_all, flagsA);
  // 4) P1 = h0 @ W_ih1^T + (b_ih1+b_hh1)    (4096 x 4096, K=1024)
  gemm_nt<<<dim3(32, 32), 256, 0, stream>>>(h0_all, W_ih1, b1sum, pre_big,
                                            T_STEPS, 4096, HID, 0);
  // 5) layer-1 recurrence -> h1 (reuses zbuf)
  lstm_layer<<<NBLK, 1024, 0, stream>>>(pre_big, W_hh1, zbuf, flagsC);
  // 6) y = h1 @ W_out^T + b_out, scattered to (samples, steps, out)
  gemm_nt<<<dim3(32, 1), 256, 0, stream>>>(zbuf, W_out, b_out, out,
                                           T_STEPS, 64, HID, 1);
}

// Round 3
// 23736.015 us; speedup vs baseline: 8.7088x; 1.4404x over previous
//
#include <hip/hip_runtime.h>
#include <math.h>

// ---------------------------------------------------------------------------
// SimpleRNN (2-layer LSTM, H=1024, T=4096 sequential steps, batch=1 effective)
//
//   k_prep     : gather x (step-major), combine biases, zero sync flags
//   gemm_nt    : C[M,N] = A[M,K] @ B[N,K]^T + bias
//   lstm_fused : ONE persistent 256-block kernel running BOTH layer chains,
//                layer-1 pipelined one step behind layer-0 (4097 rounds
//                instead of 2*4096).
//                 blocks 0..127  : layer 0, 8 units, W_hh0 in LDS (128 KB),
//                                  polls only the 128 layer-0 flags.
//                 blocks 128..255: layer 1, 8 units, W_hh1 in LDS (128 KB),
//                                  W_ih1 rows held in 32 VGPRs/thread
//                                  (input matvec computed online -> the big
//                                  P1 GEMM is gone), polls all 256 flags.
//                Sync: per-block release-store flag on its own 64B line.
// ---------------------------------------------------------------------------

#define T_STEPS 4096
#define HID 1024
#define UPB 8            // hidden units per block
#define NBLK 256         // total persistent blocks (128 per layer)
#define FPAD 16          // ints per flag slot (64 B)

__global__ void k_prep(const float* __restrict__ inputs,
                       const float* __restrict__ b_ih0, const float* __restrict__ b_hh0,
                       const float* __restrict__ b_ih1, const float* __restrict__ b_hh1,
                       float* __restrict__ xg, float* __restrict__ bsum0,
                       float* __restrict__ b1sum, int* __restrict__ flags) {
  int i = blockIdx.x * 256 + threadIdx.x;   // grid covers 262144
  if (i < T_STEPS * 64) {
    int t = i >> 6, d = i & 63;
    // x[t] = inputs[sample = t%32, step = t/32, :]
    xg[i] = inputs[(t & 31) * 8192 + (t >> 5) * 64 + d];
  }
  if (i < 4096) {
    bsum0[i] = b_ih0[i] + b_hh0[i];
    b1sum[i] = b_ih1[i] + b_hh1[i];
  }
  if (i < NBLK * FPAD) flags[i] = 0;
}

// C = A @ B^T + bias.  A: M x K, B: N x K (both row-major, K contiguous).
// 128x128 tile, BK=8, 256 threads, 8x8 micro-tile per thread.
__global__ __launch_bounds__(256) void gemm_nt(
    const float* __restrict__ A, const float* __restrict__ B,
    const float* __restrict__ bias, float* __restrict__ C,
    int M, int N, int K, int mode) {
  __shared__ float As[8][128];
  __shared__ float Bs[8][128];
  const int tid = threadIdx.x;
  const int bm = blockIdx.x * 128;
  const int bn = blockIdx.y * 128;
  const int tm = tid >> 4;
  const int tn = tid & 15;
  const int lr = tid >> 1;
  const int lk = (tid & 1) * 4;

  float acc[8][8];
#pragma unroll
  for (int i = 0; i < 8; i++)
#pragma unroll
    for (int j = 0; j < 8; j++) acc[i][j] = 0.f;

  const float* Ap = A + (long)(bm + lr) * K + lk;
  const bool bvalid = (bn + lr) < N;
  const float* Bp = B + (long)(bvalid ? (bn + lr) : 0) * K + lk;

  for (int k0 = 0; k0 < K; k0 += 8) {
    float4 av = *(const float4*)(Ap + k0);
    float4 bv = bvalid ? *(const float4*)(Bp + k0) : make_float4(0.f, 0.f, 0.f, 0.f);
    As[lk + 0][lr] = av.x; As[lk + 1][lr] = av.y;
    As[lk + 2][lr] = av.z; As[lk + 3][lr] = av.w;
    Bs[lk + 0][lr] = bv.x; Bs[lk + 1][lr] = bv.y;
    Bs[lk + 2][lr] = bv.z; Bs[lk + 3][lr] = bv.w;
    __syncthreads();
#pragma unroll
    for (int kk = 0; kk < 8; kk++) {
      float a[8], b[8];
      *(float4*)&a[0] = *(const float4*)&As[kk][tm * 8];
      *(float4*)&a[4] = *(const float4*)&As[kk][tm * 8 + 4];
      *(float4*)&b[0] = *(const float4*)&Bs[kk][tn * 8];
      *(float4*)&b[4] = *(const float4*)&Bs[kk][tn * 8 + 4];
#pragma unroll
      for (int i = 0; i < 8; i++)
#pragma unroll
        for (int j = 0; j < 8; j++) acc[i][j] = fmaf(a[i], b[j], acc[i][j]);
    }
    __syncthreads();
  }

  const int n0 = bn + tn * 8;
  if (n0 < N) {
    float bb[8];
#pragma unroll
    for (int j = 0; j < 8; j++) bb[j] = bias[n0 + j];
#pragma unroll
    for (int i = 0; i < 8; i++) {
      int m = bm + tm * 8 + i;
      float4 v0, v1;
      v0.x = acc[i][0] + bb[0]; v0.y = acc[i][1] + bb[1];
      v0.z = acc[i][2] + bb[2]; v0.w = acc[i][3] + bb[3];
      v1.x = acc[i][4] + bb[4]; v1.y = acc[i][5] + bb[5];
      v1.z = acc[i][6] + bb[6]; v1.w = acc[i][7] + bb[7];
      if (mode == 0) {
        long o = (long)m * N + n0;
        *(float4*)&C[o] = v0; *(float4*)&C[o + 4] = v1;
      } else {
        long o = (long)(m & 31) * 8192 + (long)(m >> 5) * 64 + n0;
        *(float4*)&C[o] = v0; *(float4*)&C[o + 4] = v1;
      }
    }
  }
}

__device__ __forceinline__ float sigmf(float x) { return 1.f / (1.f + expf(-x)); }

#define AGENT_LD(p) __hip_atomic_load((p), __ATOMIC_RELAXED, __HIP_MEMORY_SCOPE_AGENT)
#define AGENT_ST(p, v) __hip_atomic_store((p), (v), __ATOMIC_RELAXED, __HIP_MEMORY_SCOPE_AGENT)

// Fused 2-layer recurrence. 256 blocks x 1024 threads, 1 block/CU (136 KB LDS).
__global__ __launch_bounds__(1024, 1) void lstm_fused(
    const float* __restrict__ pre0,   // T x 4096 (all layer-0 biases included)
    const float* __restrict__ Whh0,   // 4096 x 1024
    const float* __restrict__ Wih1,   // 4096 x 1024
    const float* __restrict__ Whh1,   // 4096 x 1024
    const float* __restrict__ b1sum,  // 4096
    float* __restrict__ h0_hist,      // T x 1024
    float* __restrict__ h1_hist,      // T x 1024
    int* __restrict__ flags) {        // NBLK slots, FPAD ints apart
  __shared__ float w_lds[32][HID];    // 128 KB, layer's W_hh rows
  __shared__ float ha_lds[HID];       // 4 KB
  __shared__ float hb_lds[HID];       // 4 KB (layer-1 only)
  __shared__ float scr[32];
  __shared__ float pre_lds[32];
  const int b = blockIdx.x;
  const int tid = threadIdx.x;
  const int wave = tid >> 6;          // wave w owns local rows 2w, 2w+1
  const int lane = tid & 63;

  if (b < 128) {
    // ----------------------------- layer 0 -------------------------------
    const int j0 = b * UPB;
    {
      int rr = tid >> 5, part = tid & 31;
      const float* src = Whh0 + (long)((rr >> 3) * HID + j0 + (rr & 7)) * HID + part * 32;
      float* dst = &w_lds[rr][part * 32];
#pragma unroll
      for (int q = 0; q < 8; q++)
        *(float4*)(dst + q * 4) = *(const float4*)(src + q * 4);
    }
    float c_state = 0.f;              // valid in tid 0..7
    __syncthreads();

    for (int t = 0; t < T_STEPS; t++) {
      float preval = 0.f;             // prefetch overlaps the poll
      if (tid < 32)
        preval = pre0[(long)t * 4096 + ((tid >> 3) << 10) + j0 + (tid & 7)];

      if (t > 0) {
        if (wave == 0) {              // poll ONLY the 128 layer-0 flags
          const int* f0 = flags + lane * FPAD;
          const int* f1 = flags + (lane + 64) * FPAD;
          for (;;) {
            int a = AGENT_LD(f0);
            int c = AGENT_LD(f1);
            if (__all(a >= t && c >= t)) break;
            __builtin_amdgcn_s_sleep(1);
          }
        }
        __syncthreads();
        ha_lds[tid] = AGENT_LD(h0_hist + (long)(t - 1) * HID + tid);
      } else {
        ha_lds[tid] = 0.f;
      }
      if (tid < 32) pre_lds[tid] = preval;
      __syncthreads();

      const float* w0 = &w_lds[wave * 2 + 0][0];
      const float* w1 = &w_lds[wave * 2 + 1][0];
      float s0 = 0.f, s1 = 0.f;
#pragma unroll
      for (int m = 0; m < 16; m++) {
        float hv = ha_lds[lane + (m << 6)];
        s0 = fmaf(w0[lane + (m << 6)], hv, s0);
        s1 = fmaf(w1[lane + (m << 6)], hv, s1);
      }
#pragma unroll
      for (int off = 32; off >= 1; off >>= 1) {
        s0 += __shfl_xor(s0, off, 64);
        s1 += __shfl_xor(s1, off, 64);
      }
      if (lane == 0) { scr[wave * 2] = s0; scr[wave * 2 + 1] = s1; }
      __syncthreads();

      if (tid < UPB) {
        float gi = scr[tid]      + pre_lds[tid];
        float gf = scr[8 + tid]  + pre_lds[8 + tid];
        float gg = scr[16 + tid] + pre_lds[16 + tid];
        float go = scr[24 + tid] + pre_lds[24 + tid];
        c_state = sigmf(gf) * c_state + sigmf(gi) * tanhf(gg);
        AGENT_ST(&h0_hist[(long)t * HID + j0 + tid], sigmf(go) * tanhf(c_state));
      }
      __syncthreads();                // drains h stores (vmcnt) before release
      if (tid == 0)
        __hip_atomic_store(&flags[b * FPAD], t + 1, __ATOMIC_RELEASE,
                           __HIP_MEMORY_SCOPE_AGENT);
    }
  } else {
    // ----------------------------- layer 1 -------------------------------
    const int j0 = (b - 128) * UPB;
    {
      int rr = tid >> 5, part = tid & 31;
      const float* src = Whh1 + (long)((rr >> 3) * HID + j0 + (rr & 7)) * HID + part * 32;
      float* dst = &w_lds[rr][part * 32];
#pragma unroll
      for (int q = 0; q < 8; q++)
        *(float4*)(dst + q * 4) = *(const float4*)(src + q * 4);
    }
    // W_ih1 rows for this block, held in registers in dot layout:
    // wih[u*16+m] = W_ih1[local row 2*wave+u][lane + 64*m]
    float wih[32];
#pragma unroll
    for (int u = 0; u < 2; u++) {
      int rr = wave * 2 + u;
      const float* src = Wih1 + (long)((rr >> 3) * HID + j0 + (rr & 7)) * HID + lane;
#pragma unroll
      for (int m = 0; m < 16; m++) wih[u * 16 + m] = src[m << 6];
    }
    if (tid < 32)
      pre_lds[tid] = b1sum[((tid >> 3) << 10) + j0 + (tid & 7)];  // constant bias
    float c_state = 0.f;              // valid in tid 0..7
    __syncthreads();

    // round 0: nothing to compute, announce readiness
    if (tid == 0)
      __hip_atomic_store(&flags[b * FPAD], 1, __ATOMIC_RELEASE,
                         __HIP_MEMORY_SCOPE_AGENT);

    for (int r = 1; r <= T_STEPS; r++) {   // computes h1[r-1]
      if (wave == 0) {                // poll all 256 flags (L0 + L1)
        const int* fp = flags + (lane * 4) * FPAD;
        for (;;) {
          int a0 = AGENT_LD(fp + 0 * FPAD);
          int a1 = AGENT_LD(fp + 1 * FPAD);
          int a2 = AGENT_LD(fp + 2 * FPAD);
          int a3 = AGENT_LD(fp + 3 * FPAD);
          if (__all(a0 >= r && a1 >= r && a2 >= r && a3 >= r)) break;
          __builtin_amdgcn_s_sleep(1);
        }
      }
      __syncthreads();
      float h0v = AGENT_LD(h0_hist + (long)(r - 1) * HID + tid);
      float h1v = (r >= 2) ? AGENT_LD(h1_hist + (long)(r - 2) * HID + tid) : 0.f;
      ha_lds[tid] = h0v;
      hb_lds[tid] = h1v;
      __syncthreads();

      const float* w0 = &w_lds[wave * 2 + 0][0];
      const float* w1 = &w_lds[wave * 2 + 1][0];
      float s0 = 0.f, s1 = 0.f;
#pragma unroll
      for (int m = 0; m < 16; m++) {
        float av = ha_lds[lane + (m << 6)];
        float bv = hb_lds[lane + (m << 6)];
        s0 = fmaf(wih[m], av, s0);
        s0 = fmaf(w0[lane + (m << 6)], bv, s0);
        s1 = fmaf(wih[16 + m], av, s1);
        s1 = fmaf(w1[lane + (m << 6)], bv, s1);
      }
#pragma unroll
      for (int off = 32; off >= 1; off >>= 1) {
        s0 += __shfl_xor(s0, off, 64);
        s1 += __shfl_xor(s1, off, 64);
      }
      if (lane == 0) { scr[wave * 2] = s0; scr[wave * 2 + 1] = s1; }
      __syncthreads();

      if (tid < UPB) {
        float gi = scr[tid]      + pre_lds[tid];
        float gf = scr[8 + tid]  + pre_lds[8 + tid];
        float gg = scr[16 + tid] + pre_lds[16 + tid];
        float go = scr[24 + tid] + pre_lds[24 + tid];
        c_state = sigmf(gf) * c_state + sigmf(gi) * tanhf(gg);
        AGENT_ST(&h1_hist[(long)(r - 1) * HID + j0 + tid], sigmf(go) * tanhf(c_state));
      }
      __syncthreads();
      if (tid == 0)
        __hip_atomic_store(&flags[b * FPAD], r + 1, __ATOMIC_RELEASE,
                           __HIP_MEMORY_SCOPE_AGENT);
    }
  }
}

extern "C" void kernel_launch(void* const* d_in, const int* in_sizes, int n_in,
                              void* d_out, int out_size, void* d_ws, size_t ws_size,
                              hipStream_t stream) {
  const float* inputs = (const float*)d_in[0];
  const float* W_in  = (const float*)d_in[1];
  const float* b_in  = (const float*)d_in[2];
  const float* W_ih0 = (const float*)d_in[3];
  const float* W_hh0 = (const float*)d_in[4];
  const float* b_ih0 = (const float*)d_in[5];
  const float* b_hh0 = (const float*)d_in[6];
  const float* W_ih1 = (const float*)d_in[7];
  const float* W_hh1 = (const float*)d_in[8];
  const float* b_ih1 = (const float*)d_in[9];
  const float* b_hh1 = (const float*)d_in[10];
  const float* W_out = (const float*)d_in[11];
  const float* b_out = (const float*)d_in[12];
  float* out = (float*)d_out;

  char* ws = (char*)d_ws;
  float* pre_big = (float*)(ws);                          // 64 MB: pre0
  float* h0_all  = (float*)(ws + ((size_t)64 << 20));     // 16 MB
  float* zbuf    = (float*)(ws + ((size_t)80 << 20));     // 16 MB: z, then h1
  float* xg      = (float*)(ws + ((size_t)96 << 20));     // 1 MB
  float* bsum0   = (float*)(ws + ((size_t)97 << 20));     // 16 KB
  float* b1sum   = (float*)(ws + ((size_t)97 << 20) + 16384);
  int*   flags   = (int*)  (ws + ((size_t)97 << 20) + 32768);  // NBLK*FPAD ints

  // 0) gather x, combine biases, zero flags
  k_prep<<<1024, 256, 0, stream>>>(inputs, b_ih0, b_hh0, b_ih1, b_hh1,
                                   xg, bsum0, b1sum, flags);
  // 1) z = x @ W_in^T + b_in            (4096 x 1024, K=64)
  gemm_nt<<<dim3(32, 8), 256, 0, stream>>>(xg, W_in, b_in, zbuf,
                                           T_STEPS, HID, 64, 0);
  // 2) pre0 = z @ W_ih0^T + (b_ih0+b_hh0)   (4096 x 4096, K=1024)
  gemm_nt<<<dim3(32, 32), 256, 0, stream>>>(zbuf, W_ih0, bsum0, pre_big,
                                            T_STEPS, 4096, HID, 0);
  // 3) fused 2-layer pipelined recurrence -> h0_all, zbuf(=h1)
  lstm_fused<<<NBLK, 1024, 0, stream>>>(pre_big, W_hh0, W_ih1, W_hh1, b1sum,
                                        h0_all, zbuf, flags);
  // 4) y = h1 @ W_out^T + b_out, scattered to (samples, steps, out)
  gemm_nt<<<dim3(32, 1), 256, 0, stream>>>(zbuf, W_out, b_out, out,
                                           T_STEPS, 64, HID, 1);
}

// Round 4
// 13487.169 us; speedup vs baseline: 15.3265x; 1.7599x over previous
//
#include <hip/hip_runtime.h>
#include <math.h>

// ---------------------------------------------------------------------------
// SimpleRNN (2-layer LSTM, H=1024, T=4096 sequential steps, batch=1 effective)
//
//   k_clear    : zero the packet buffers (tags must start invalid)
//   k_prep     : gather x (step-major), combine biases
//   gemm_nt    : C[M,N] = A[M,K] @ B[N,K]^T + bias
//   lstm_fused : ONE persistent 256-block kernel, both layer chains, layer-1
//                pipelined one step behind layer-0 (4097 rounds).
//                SYNC = DATA: h values travel as 8-byte packets
//                {float h, int tag = step+1} written with ONE relaxed
//                agent-scope 64-bit store. Consumers poll the packet itself;
//                tag validity implies payload validity (same atom). No flags,
//                no release fences, ONE MALL round trip per step.
// ---------------------------------------------------------------------------

#define T_STEPS 4096
#define HID 1024
#define UPB 8            // hidden units per block
#define NBLK 256         // persistent blocks (128 per layer)

typedef unsigned long long u64;

#define AGENT_LD64(p) __hip_atomic_load((p), __ATOMIC_RELAXED, __HIP_MEMORY_SCOPE_AGENT)
#define AGENT_ST64(p, v) __hip_atomic_store((p), (v), __ATOMIC_RELAXED, __HIP_MEMORY_SCOPE_AGENT)

__device__ __forceinline__ u64 pack_h(float h, int tag) {
  return (u64)__float_as_uint(h) | ((u64)(unsigned)tag << 32);
}
__device__ __forceinline__ float pkt_val(u64 v) { return __uint_as_float((unsigned)v); }
__device__ __forceinline__ int pkt_tag(u64 v) { return (int)(v >> 32); }

__global__ void k_clear(u64* __restrict__ p, long n) {
  long i = (long)blockIdx.x * blockDim.x + threadIdx.x;
  long stride = (long)gridDim.x * blockDim.x;
  for (; i < n; i += stride) p[i] = 0ULL;
}

__global__ void k_prep(const float* __restrict__ inputs,
                       const float* __restrict__ b_ih0, const float* __restrict__ b_hh0,
                       const float* __restrict__ b_ih1, const float* __restrict__ b_hh1,
                       float* __restrict__ xg, float* __restrict__ bsum0,
                       float* __restrict__ b1sum) {
  int i = blockIdx.x * 256 + threadIdx.x;   // grid covers 262144
  if (i < T_STEPS * 64) {
    int t = i >> 6, d = i & 63;
    // x[t] = inputs[sample = t%32, step = t/32, :]
    xg[i] = inputs[(t & 31) * 8192 + (t >> 5) * 64 + d];
  }
  if (i < 4096) {
    bsum0[i] = b_ih0[i] + b_hh0[i];
    b1sum[i] = b_ih1[i] + b_hh1[i];
  }
}

// C = A @ B^T + bias.  A: M x K, B: N x K (both row-major, K contiguous).
// 128x128 tile, BK=8, 256 threads, 8x8 micro-tile per thread.
__global__ __launch_bounds__(256) void gemm_nt(
    const float* __restrict__ A, const float* __restrict__ B,
    const float* __restrict__ bias, float* __restrict__ C,
    int M, int N, int K, int mode) {
  __shared__ float As[8][128];
  __shared__ float Bs[8][128];
  const int tid = threadIdx.x;
  const int bm = blockIdx.x * 128;
  const int bn = blockIdx.y * 128;
  const int tm = tid >> 4;
  const int tn = tid & 15;
  const int lr = tid >> 1;
  const int lk = (tid & 1) * 4;

  float acc[8][8];
#pragma unroll
  for (int i = 0; i < 8; i++)
#pragma unroll
    for (int j = 0; j < 8; j++) acc[i][j] = 0.f;

  const float* Ap = A + (long)(bm + lr) * K + lk;
  const bool bvalid = (bn + lr) < N;
  const float* Bp = B + (long)(bvalid ? (bn + lr) : 0) * K + lk;

  for (int k0 = 0; k0 < K; k0 += 8) {
    float4 av = *(const float4*)(Ap + k0);
    float4 bv = bvalid ? *(const float4*)(Bp + k0) : make_float4(0.f, 0.f, 0.f, 0.f);
    As[lk + 0][lr] = av.x; As[lk + 1][lr] = av.y;
    As[lk + 2][lr] = av.z; As[lk + 3][lr] = av.w;
    Bs[lk + 0][lr] = bv.x; Bs[lk + 1][lr] = bv.y;
    Bs[lk + 2][lr] = bv.z; Bs[lk + 3][lr] = bv.w;
    __syncthreads();
#pragma unroll
    for (int kk = 0; kk < 8; kk++) {
      float a[8], b[8];
      *(float4*)&a[0] = *(const float4*)&As[kk][tm * 8];
      *(float4*)&a[4] = *(const float4*)&As[kk][tm * 8 + 4];
      *(float4*)&b[0] = *(const float4*)&Bs[kk][tn * 8];
      *(float4*)&b[4] = *(const float4*)&Bs[kk][tn * 8 + 4];
#pragma unroll
      for (int i = 0; i < 8; i++)
#pragma unroll
        for (int j = 0; j < 8; j++) acc[i][j] = fmaf(a[i], b[j], acc[i][j]);
    }
    __syncthreads();
  }

  const int n0 = bn + tn * 8;
  if (n0 < N) {
    float bb[8];
#pragma unroll
    for (int j = 0; j < 8; j++) bb[j] = bias[n0 + j];
#pragma unroll
    for (int i = 0; i < 8; i++) {
      int m = bm + tm * 8 + i;
      float4 v0, v1;
      v0.x = acc[i][0] + bb[0]; v0.y = acc[i][1] + bb[1];
      v0.z = acc[i][2] + bb[2]; v0.w = acc[i][3] + bb[3];
      v1.x = acc[i][4] + bb[4]; v1.y = acc[i][5] + bb[5];
      v1.z = acc[i][6] + bb[6]; v1.w = acc[i][7] + bb[7];
      if (mode == 0) {
        long o = (long)m * N + n0;
        *(float4*)&C[o] = v0; *(float4*)&C[o + 4] = v1;
      } else {
        long o = (long)(m & 31) * 8192 + (long)(m >> 5) * 64 + n0;
        *(float4*)&C[o] = v0; *(float4*)&C[o + 4] = v1;
      }
    }
  }
}

__device__ __forceinline__ float sigmf(float x) { return 1.f / (1.f + expf(-x)); }

// Fused 2-layer recurrence. 256 blocks x 1024 threads, 1 block/CU (~136 KB LDS).
__global__ __launch_bounds__(1024, 1) void lstm_fused(
    const float* __restrict__ pre0,   // T x 4096 (layer-0 biases included)
    const float* __restrict__ Whh0,   // 4096 x 1024
    const float* __restrict__ Wih1,   // 4096 x 1024
    const float* __restrict__ Whh1,   // 4096 x 1024
    const float* __restrict__ b1sum,  // 4096
    u64* __restrict__ pk0,            // T x 1024 packets {h0, tag=t+1}
    u64* __restrict__ pk1,            // T x 1024 packets {h1, tag=t+1}
    float* __restrict__ h1_hist) {    // T x 1024 plain (for output GEMM)
  __shared__ float w_lds[32][HID];    // 128 KB, this layer's W_hh rows
  __shared__ float ha_lds[HID];       // 4 KB
  __shared__ float hb_lds[HID];       // 4 KB (layer-1 only)
  __shared__ float scr[32];
  __shared__ float pre_lds[32];
  const int b = blockIdx.x;
  const int tid = threadIdx.x;
  const int wave = tid >> 6;          // wave w owns local rows 2w, 2w+1
  const int lane = tid & 63;

  if (b < 128) {
    // ----------------------------- layer 0 -------------------------------
    const int j0 = b * UPB;
    {
      int rr = tid >> 5, part = tid & 31;
      const float* src = Whh0 + (long)((rr >> 3) * HID + j0 + (rr & 7)) * HID + part * 32;
      float* dst = &w_lds[rr][part * 32];
#pragma unroll
      for (int q = 0; q < 8; q++)
        *(float4*)(dst + q * 4) = *(const float4*)(src + q * 4);
    }
    float c_state = 0.f;              // valid in tid 0..7
    __syncthreads();

    for (int t = 0; t < T_STEPS; t++) {
      float preval = 0.f;             // prefetch overlaps the poll
      if (tid < 32)
        preval = pre0[(long)t * 4096 + ((tid >> 3) << 10) + j0 + (tid & 7)];

      if (t > 0) {
        // each thread polls its own unit's packet for step t-1 (tag == t)
        const u64* p = pk0 + (long)(t - 1) * HID + tid;
        u64 v;
        for (;;) {
          v = AGENT_LD64(p);
          if (pkt_tag(v) == t) break;
          __builtin_amdgcn_s_sleep(1);
        }
        ha_lds[tid] = pkt_val(v);
      } else {
        ha_lds[tid] = 0.f;
      }
      if (tid < 32) pre_lds[tid] = preval;
      __syncthreads();

      const float* w0 = &w_lds[wave * 2 + 0][0];
      const float* w1 = &w_lds[wave * 2 + 1][0];
      float s0 = 0.f, s1 = 0.f;
#pragma unroll
      for (int m = 0; m < 16; m++) {
        float hv = ha_lds[lane + (m << 6)];
        s0 = fmaf(w0[lane + (m << 6)], hv, s0);
        s1 = fmaf(w1[lane + (m << 6)], hv, s1);
      }
#pragma unroll
      for (int off = 32; off >= 1; off >>= 1) {
        s0 += __shfl_xor(s0, off, 64);
        s1 += __shfl_xor(s1, off, 64);
      }
      if (lane == 0) { scr[wave * 2] = s0; scr[wave * 2 + 1] = s1; }
      __syncthreads();

      if (tid < UPB) {
        float gi = scr[tid]      + pre_lds[tid];
        float gf = scr[8 + tid]  + pre_lds[8 + tid];
        float gg = scr[16 + tid] + pre_lds[16 + tid];
        float go = scr[24 + tid] + pre_lds[24 + tid];
        c_state = sigmf(gf) * c_state + sigmf(gi) * tanhf(gg);
        float h = sigmf(go) * tanhf(c_state);
        // data + tag in one atomic 8B store: sync IS the data
        AGENT_ST64(&pk0[(long)t * HID + j0 + tid], pack_h(h, t + 1));
      }
      // no barrier/fence needed before next round: tag travels with payload
    }
  } else {
    // ----------------------------- layer 1 -------------------------------
    const int j0 = (b - 128) * UPB;
    {
      int rr = tid >> 5, part = tid & 31;
      const float* src = Whh1 + (long)((rr >> 3) * HID + j0 + (rr & 7)) * HID + part * 32;
      float* dst = &w_lds[rr][part * 32];
#pragma unroll
      for (int q = 0; q < 8; q++)
        *(float4*)(dst + q * 4) = *(const float4*)(src + q * 4);
    }
    // W_ih1 rows for this block in dot layout:
    // wih[u*16+m] = W_ih1[local row 2*wave+u][lane + 64*m]
    float wih[32];
#pragma unroll
    for (int u = 0; u < 2; u++) {
      int rr = wave * 2 + u;
      const float* src = Wih1 + (long)((rr >> 3) * HID + j0 + (rr & 7)) * HID + lane;
#pragma unroll
      for (int m = 0; m < 16; m++) wih[u * 16 + m] = src[m << 6];
    }
    if (tid < 32)
      pre_lds[tid] = b1sum[((tid >> 3) << 10) + j0 + (tid & 7)];  // constant bias
    float c_state = 0.f;              // valid in tid 0..7
    __syncthreads();

    for (int r = 1; r <= T_STEPS; r++) {   // computes h1[r-1]
      // poll h0[r-1] (tag r) and, if r>=2, h1[r-2] (tag r-1) concurrently
      const u64* p0 = pk0 + (long)(r - 1) * HID + tid;
      const u64* p1 = pk1 + (long)((r >= 2) ? (r - 2) : 0) * HID + tid;
      u64 v0 = 0, v1 = 0;
      bool ok0 = false, ok1 = (r < 2);
      for (;;) {
        if (!ok0) { v0 = AGENT_LD64(p0); ok0 = (pkt_tag(v0) == r); }
        if (!ok1) { v1 = AGENT_LD64(p1); ok1 = (pkt_tag(v1) == r - 1); }
        if (ok0 && ok1) break;
        __builtin_amdgcn_s_sleep(1);
      }
      ha_lds[tid] = pkt_val(v0);
      hb_lds[tid] = (r >= 2) ? pkt_val(v1) : 0.f;
      __syncthreads();

      const float* w0 = &w_lds[wave * 2 + 0][0];
      const float* w1 = &w_lds[wave * 2 + 1][0];
      float s0 = 0.f, s1 = 0.f;
#pragma unroll
      for (int m = 0; m < 16; m++) {
        float av = ha_lds[lane + (m << 6)];
        float bv = hb_lds[lane + (m << 6)];
        s0 = fmaf(wih[m], av, s0);
        s0 = fmaf(w0[lane + (m << 6)], bv, s0);
        s1 = fmaf(wih[16 + m], av, s1);
        s1 = fmaf(w1[lane + (m << 6)], bv, s1);
      }
#pragma unroll
      for (int off = 32; off >= 1; off >>= 1) {
        s0 += __shfl_xor(s0, off, 64);
        s1 += __shfl_xor(s1, off, 64);
      }
      if (lane == 0) { scr[wave * 2] = s0; scr[wave * 2 + 1] = s1; }
      __syncthreads();

      if (tid < UPB) {
        float gi = scr[tid]      + pre_lds[tid];
        float gf = scr[8 + tid]  + pre_lds[8 + tid];
        float gg = scr[16 + tid] + pre_lds[16 + tid];
        float go = scr[24 + tid] + pre_lds[24 + tid];
        c_state = sigmf(gf) * c_state + sigmf(gi) * tanhf(gg);
        float h = sigmf(go) * tanhf(c_state);
        AGENT_ST64(&pk1[(long)(r - 1) * HID + j0 + tid], pack_h(h, r));
        h1_hist[(long)(r - 1) * HID + j0 + tid] = h;   // off-path, for out GEMM
      }
    }
  }
}

extern "C" void kernel_launch(void* const* d_in, const int* in_sizes, int n_in,
                              void* d_out, int out_size, void* d_ws, size_t ws_size,
                              hipStream_t stream) {
  const float* inputs = (const float*)d_in[0];
  const float* W_in  = (const float*)d_in[1];
  const float* b_in  = (const float*)d_in[2];
  const float* W_ih0 = (const float*)d_in[3];
  const float* W_hh0 = (const float*)d_in[4];
  const float* b_ih0 = (const float*)d_in[5];
  const float* b_hh0 = (const float*)d_in[6];
  const float* W_ih1 = (const float*)d_in[7];
  const float* W_hh1 = (const float*)d_in[8];
  const float* b_ih1 = (const float*)d_in[9];
  const float* b_hh1 = (const float*)d_in[10];
  const float* W_out = (const float*)d_in[11];
  const float* b_out = (const float*)d_in[12];
  float* out = (float*)d_out;

  char* ws = (char*)d_ws;
  float* pre_big = (float*)(ws);                          // [0,64) MB: pre0
  u64*   pk0     = (u64*)  (ws + ((size_t)64 << 20));     // [64,96) MB
  u64*   pk1     = (u64*)  (ws + ((size_t)96 << 20));     // [96,128) MB
  float* zbuf    = (float*)(ws + ((size_t)128 << 20));    // [128,144) MB: z, then h1
  float* xg      = (float*)(ws + ((size_t)144 << 20));    // 1 MB
  float* bsum0   = (float*)(ws + ((size_t)145 << 20));    // 16 KB
  float* b1sum   = (float*)(ws + ((size_t)145 << 20) + 16384);

  // 0) invalidate packet tags (64 MB zeros) + gather x + combine biases
  k_clear<<<2048, 256, 0, stream>>>(pk0, (long)2 * T_STEPS * HID);
  k_prep<<<1024, 256, 0, stream>>>(inputs, b_ih0, b_hh0, b_ih1, b_hh1,
                                   xg, bsum0, b1sum);
  // 1) z = x @ W_in^T + b_in            (4096 x 1024, K=64)
  gemm_nt<<<dim3(32, 8), 256, 0, stream>>>(xg, W_in, b_in, zbuf,
                                           T_STEPS, HID, 64, 0);
  // 2) pre0 = z @ W_ih0^T + (b_ih0+b_hh0)   (4096 x 4096, K=1024)
  gemm_nt<<<dim3(32, 32), 256, 0, stream>>>(zbuf, W_ih0, bsum0, pre_big,
                                            T_STEPS, 4096, HID, 0);
  // 3) fused pipelined 2-layer recurrence (z already consumed; h1 -> zbuf)
  lstm_fused<<<NBLK, 1024, 0, stream>>>(pre_big, W_hh0, W_ih1, W_hh1, b1sum,
                                        pk0, pk1, zbuf);
  // 4) y = h1 @ W_out^T + b_out, scattered to (samples, steps, out)
  gemm_nt<<<dim3(32, 1), 256, 0, stream>>>(zbuf, W_out, b_out, out,
                                           T_STEPS, 64, HID, 1);
}